// Round 2
// baseline (5857.783 us; speedup 1.0000x reference)
//
#include <hip/hip_runtime.h>

#define N_OSC 50
#define N_PER 40
#define DT 0.01f
#define STEPS 100
#define BATCH 8192

// ws layout (float offsets)
#define WS_PC     0        // 50*240 packed consts
#define WS_DIRECT 12288    // 8192
#define WS_O0     20480    // 100*8192
#define WS_TORQ   839680   // 100*8192 torque accumulator

// ---------------------------------------------------------------------------
// Prep: zero torq accumulator + pack per-osc constants in SCALAR-STREAM layout
// (contiguous 40-float runs per operand so the osc kernel's uniform reads
// merge into s_load_dwordx8/x16):
//   pc[o*240 +   0.. 39] = e0[n]   (enc[o][n][0])
//   pc[o*240 +  40.. 79] = e1[n]   (enc[o][n][1])
//   pc[o*240 +  80..119] = d0[n]   (dec[o][0][n])
//   pc[o*240 + 120..159] = d1[n]   (dec[o][1][n])
//   pc[o*240 + 160..199] = w [n]   (fc4_w[o*40+n])
//   pc[o*240 + 200..239] = ob[n]   (obias[o][n])
// ---------------------------------------------------------------------------
__global__ __launch_bounds__(256) void prep_kernel(
    const float* __restrict__ enc, const float* __restrict__ obias,
    const float* __restrict__ dec, const float* __restrict__ fc4_w,
    float* __restrict__ pc, float* __restrict__ torq) {
    int idx = blockIdx.x * 256 + threadIdx.x;
    ((float4*)torq)[idx] = make_float4(0.f, 0.f, 0.f, 0.f);   // 800*256*4 = 819200
    if (idx < N_OSC * N_PER) {
        int o = idx / N_PER, n = idx - o * N_PER;
        float* base = pc + o * 240;
        base[n]       = enc[o * 80 + 2 * n + 0];
        base[40 + n]  = enc[o * 80 + 2 * n + 1];
        base[80 + n]  = dec[o * 80 + n];
        base[120 + n] = dec[o * 80 + 40 + n];
        base[160 + n] = fc4_w[o * 40 + n];
        base[200 + n] = obias[o * 40 + n];
    }
}

// ---------------------------------------------------------------------------
// MLP prologue. 1024 blocks x 256 threads, 8 batch rows per block ->
// 4 waves/SIMD to hide the L2 weight-load latency. bb = tid&7 owns a row,
// hw = tid>>3 owns a j-quad; weight addresses uniform per 8-lane group.
// ---------------------------------------------------------------------------
__global__ __launch_bounds__(256) void mlp_kernel(
    const float* __restrict__ x,
    const float* __restrict__ fc1_w, const float* __restrict__ fc1_b,
    const float* __restrict__ fc2_w, const float* __restrict__ fc2_b,
    const float* __restrict__ fc3_w, const float* __restrict__ fc3_b,
    const float* __restrict__ fcd_w, const float* __restrict__ fcd_b,
    float* __restrict__ o0out, float* __restrict__ directout) {
    __shared__ float hs[8 * 132];
    __shared__ float h2s[8 * 132];
    int tid = threadIdx.x;
    int bb = tid & 7;
    int hw = tid >> 3;             // 0..31
    int b0 = blockIdx.x * 8;

    // fc1: h = relu(x @ fc1_w.T + b1), 8x128 outputs
    for (int idx = tid; idx < 8 * 128; idx += 256) {
        int r = idx >> 7, j = idx & 127;
        float x0 = x[(b0 + r) * 2], x1 = x[(b0 + r) * 2 + 1];
        float v = fmaf(x0, fc1_w[j * 2], fmaf(x1, fc1_w[j * 2 + 1], fc1_b[j]));
        hs[r * 132 + j] = fmaxf(v, 0.f);
    }
    __syncthreads();

    // direct = h . fcd_w + fcd_b
    if (tid < 8) {
        float s = fcd_b[0];
        #pragma unroll 8
        for (int k = 0; k < 128; k += 4) {
            float4 h4 = *(const float4*)&hs[tid * 132 + k];
            float4 w4 = *(const float4*)&fcd_w[k];
            s = fmaf(h4.x, w4.x, fmaf(h4.y, w4.y, fmaf(h4.z, w4.z, fmaf(h4.w, w4.w, s))));
        }
        directout[b0 + tid] = s;
    }

    // fc2: h2 = relu(h @ fc2_w.T + b2). Each thread: 4 j for its row.
    {
        int j0 = hw * 4;
        float a0 = fc2_b[j0], a1 = fc2_b[j0 + 1], a2 = fc2_b[j0 + 2], a3 = fc2_b[j0 + 3];
        const float* w0 = fc2_w + j0 * 128;
        const float* w1 = w0 + 128;
        const float* w2 = w0 + 256;
        const float* w3 = w0 + 384;
        #pragma unroll 8
        for (int k = 0; k < 128; k += 4) {
            float4 h4 = *(const float4*)&hs[bb * 132 + k];
            float4 q0 = *(const float4*)&w0[k];
            float4 q1 = *(const float4*)&w1[k];
            float4 q2 = *(const float4*)&w2[k];
            float4 q3 = *(const float4*)&w3[k];
            a0 = fmaf(h4.x, q0.x, fmaf(h4.y, q0.y, fmaf(h4.z, q0.z, fmaf(h4.w, q0.w, a0))));
            a1 = fmaf(h4.x, q1.x, fmaf(h4.y, q1.y, fmaf(h4.z, q1.z, fmaf(h4.w, q1.w, a1))));
            a2 = fmaf(h4.x, q2.x, fmaf(h4.y, q2.y, fmaf(h4.z, q2.z, fmaf(h4.w, q2.w, a2))));
            a3 = fmaf(h4.x, q3.x, fmaf(h4.y, q3.y, fmaf(h4.z, q3.z, fmaf(h4.w, q3.w, a3))));
        }
        h2s[bb * 132 + j0]     = fmaxf(a0, 0.f);
        h2s[bb * 132 + j0 + 1] = fmaxf(a1, 0.f);
        h2s[bb * 132 + j0 + 2] = fmaxf(a2, 0.f);
        h2s[bb * 132 + j0 + 3] = fmaxf(a3, 0.f);
    }
    __syncthreads();

    // fc3: x3 = h2 @ fc3_w.T + b3 (100 outputs) -> o0out[j][b]
    {
        int j0 = hw * 4;
        if (j0 < 100) {
            float a0 = fc3_b[j0], a1 = fc3_b[j0 + 1], a2 = fc3_b[j0 + 2], a3 = fc3_b[j0 + 3];
            const float* w0 = fc3_w + j0 * 128;
            const float* w1 = w0 + 128;
            const float* w2 = w0 + 256;
            const float* w3 = w0 + 384;
            #pragma unroll 8
            for (int k = 0; k < 128; k += 4) {
                float4 h4 = *(const float4*)&h2s[bb * 132 + k];
                float4 q0 = *(const float4*)&w0[k];
                float4 q1 = *(const float4*)&w1[k];
                float4 q2 = *(const float4*)&w2[k];
                float4 q3 = *(const float4*)&w3[k];
                a0 = fmaf(h4.x, q0.x, fmaf(h4.y, q0.y, fmaf(h4.z, q0.z, fmaf(h4.w, q0.w, a0))));
                a1 = fmaf(h4.x, q1.x, fmaf(h4.y, q1.y, fmaf(h4.z, q1.z, fmaf(h4.w, q1.w, a1))));
                a2 = fmaf(h4.x, q2.x, fmaf(h4.y, q2.y, fmaf(h4.z, q2.z, fmaf(h4.w, q2.w, a2))));
                a3 = fmaf(h4.x, q3.x, fmaf(h4.y, q3.y, fmaf(h4.z, q3.z, fmaf(h4.w, q3.w, a3))));
            }
            o0out[(j0)     * BATCH + b0 + bb] = a0;
            o0out[(j0 + 1) * BATCH + b0 + bb] = a1;
            o0out[(j0 + 2) * BATCH + b0 + bb] = a2;
            o0out[(j0 + 3) * BATCH + b0 + bb] = a3;
        }
    }
}

// ---------------------------------------------------------------------------
// Phase A, scalar/SGPR redesign.
// - CDNA4 packed fp32 has no FLOP advantage (157.3 TF spec = scalar rate),
//   so scalar FMAs cost the same VALU cycles and free the SGPR operand slot.
// - Wave-uniform constants stream through the SMEM pipe each step (s_load
//   folded as the single SGPR operand of each v_fma; scalar pipe co-issues
//   with VALU -> free). Opaque "+s" on the base pointer per step blocks
//   hoisting 200 floats into registers. Only obias (40 regs) is VGPR-pinned
//   since its fma slot already carries the SGPR e0 operand.
// - COMPILE FIX vs R0: wid/osc must be derived via readfirstlane so the
//   constant pointer is provably wave-uniform (SGPR). Deriving it from
//   threadIdx.x directly makes it a VGPR value -> "+s" constraint demanded
//   an illegal VGPR->SGPR copy. Bonus: the reducer branch is now scalar.
// - Block = 5 waves = 5 consecutive oscillators, one 64-row batch group.
//   Per-step parity-double-buffered LDS reduce, ONE atomicAdd per block-step
//   by a rotating wave (write-through 160 MB -> 32.8 MB). Barrier is raw
//   s_waitcnt lgkmcnt(0)+s_barrier: __syncthreads would drain vmcnt(0) and
//   stall on the in-flight atomic every step.
// Grid: 1280 blocks (10 osc-groups x 128 bgroups) = 5 blocks/CU = 25 waves/CU
// resident in one round (needs VGPR<=72, hence launch_bounds min-waves 7).
// ---------------------------------------------------------------------------
__global__ __launch_bounds__(320, 7) void osc_kernel(const float* __restrict__ pc,
                                                     const float* __restrict__ o0init,
                                                     float* __restrict__ torq) {
    __shared__ float red[2][5][64];
    int tid = threadIdx.x;
    int lane = tid & 63;
    // Wave-uniform ids, provably scalar:
    int wid = __builtin_amdgcn_readfirstlane(tid) >> 6;   // 0..4, SGPR
    int blk = blockIdx.x;
    int g = blk >> 7;              // 0..9  (osc group)
    int bg = blk & 127;            // batch group
    int osc = g * 5 + wid;         // SGPR
    int b = bg * 64 + lane;

    const float* pco = pc + osc * 240;   // scalar address chain

    // obias -> per-lane VGPRs, pinned (the inner fma's SGPR slot is taken by
    // e0/e1, so the addend must be a VGPR; pinning stops rematerialization).
    float obv[40];
    #pragma unroll
    for (int n = 0; n < 40; ++n) obv[n] = pco[200 + n];
    #pragma unroll
    for (int n = 0; n < 40; ++n) asm volatile("" : "+v"(obv[n]));

    float s0 = o0init[(2 * osc) * BATCH + b];
    float s1 = o0init[(2 * osc + 1) * BATCH + b];

    const float* pcs = pco;
    int rw = 0;                    // rotating reducer wave
    for (int step = 0; step < STEPS; ++step) {
        // Opaque the constant base: forces per-step s_load re-fetch (SMEM,
        // K$-hot) instead of hoisting 200 floats into registers.
        asm volatile("" : "+s"(pcs));
        float tq = 0.f, D0 = 0.f, D1 = 0.f;
        #pragma unroll
        for (int n = 0; n < 40; ++n) {
            float a = fmaf(s1, pcs[40 + n], fmaf(s0, pcs[n], obv[n]));
            a = fmaxf(a, 0.f);
            tq = fmaf(a, pcs[160 + n], tq);
            D0 = fmaf(a, pcs[80 + n],  D0);
            D1 = fmaf(a, pcs[120 + n], D1);
        }
        s0 = fmaf(DT, D0, s0);
        s1 = fmaf(DT, D1, s1);

        int par = step & 1;
        red[par][wid][lane] = tq;
        // LDS-visibility barrier WITHOUT vmcnt drain (atomic stays in flight).
        asm volatile("s_waitcnt lgkmcnt(0)\n\ts_barrier" ::: "memory");
        if (wid == rw) {           // scalar branch (wid, rw both SGPR)
            float t = red[par][0][lane] + red[par][1][lane] + red[par][2][lane]
                    + red[par][3][lane] + red[par][4][lane];
            atomicAdd(&torq[step * BATCH + b], t);
        }
        rw = (rw == 4) ? 0 : rw + 1;
    }
}

// ---------------------------------------------------------------------------
// Phase B: integrate pendulum; prefetch torq; packed float2 state store.
// ---------------------------------------------------------------------------
__global__ __launch_bounds__(256) void pend_kernel(const float* __restrict__ x,
                                                   const float* __restrict__ torq,
                                                   const float* __restrict__ direct,
                                                   const float* __restrict__ fc4_b,
                                                   float* __restrict__ out) {
    int b = blockIdx.x * 256 + threadIdx.x;
    float theta = x[2 * b];
    float omega = 0.f;
    float base = direct[b] + fc4_b[0];
    float2* out_l = (float2*)out;             // (100, 8192, 2)
    float* out_t = out + STEPS * BATCH * 2;   // (100, 8192)
    float pf[4];
    #pragma unroll
    for (int j = 0; j < 4; ++j) pf[j] = torq[j * BATCH + b];
    #pragma unroll 4
    for (int s = 0; s < STEPS; ++s) {
        float tq = base + pf[s & 3];
        if (s + 4 < STEPS) pf[s & 3] = torq[(s + 4) * BATCH + b];
        float alpha = tq - __sinf(theta) - 0.1f * omega;   // old theta, old omega
        theta = fmaf(DT, omega, theta);                    // uses old omega
        omega = fmaf(DT, alpha, omega);
        out_l[s * BATCH + b] = make_float2(theta, omega);
        out_t[s * BATCH + b] = tq;
    }
}

extern "C" void kernel_launch(void* const* d_in, const int* in_sizes, int n_in,
                              void* d_out, int out_size, void* d_ws, size_t ws_size,
                              hipStream_t stream) {
    const float* x     = (const float*)d_in[0];
    const float* fc1_w = (const float*)d_in[1];
    const float* fc1_b = (const float*)d_in[2];
    const float* fc2_w = (const float*)d_in[3];
    const float* fc2_b = (const float*)d_in[4];
    const float* fc3_w = (const float*)d_in[5];
    const float* fc3_b = (const float*)d_in[6];
    const float* fcd_w = (const float*)d_in[7];
    const float* fcd_b = (const float*)d_in[8];
    const float* enc   = (const float*)d_in[9];
    const float* obias = (const float*)d_in[10];
    const float* dec   = (const float*)d_in[11];
    const float* fc4_w = (const float*)d_in[12];
    const float* fc4_b = (const float*)d_in[13];
    float* out = (float*)d_out;
    float* ws = (float*)d_ws;

    float* pc      = ws + WS_PC;
    float* direct  = ws + WS_DIRECT;
    float* o0      = ws + WS_O0;
    float* torq    = ws + WS_TORQ;

    hipLaunchKernelGGL(prep_kernel, dim3(STEPS * BATCH / 4 / 256), dim3(256), 0, stream,
                       enc, obias, dec, fc4_w, pc, torq);
    hipLaunchKernelGGL(mlp_kernel, dim3(BATCH / 8), dim3(256), 0, stream,
                       x, fc1_w, fc1_b, fc2_w, fc2_b, fc3_w, fc3_b,
                       fcd_w, fcd_b, o0, direct);
    hipLaunchKernelGGL(osc_kernel, dim3(10 * 128), dim3(320), 0, stream,
                       pc, o0, torq);
    hipLaunchKernelGGL(pend_kernel, dim3(BATCH / 256), dim3(256), 0, stream,
                       x, torq, direct, fc4_b, out);
}

// Round 3
// 1220.978 us; speedup vs baseline: 4.7976x; 4.7976x over previous
//
#include <hip/hip_runtime.h>

#define N_OSC 50
#define N_PER 40
#define DT 0.01f
#define STEPS 100
#define BATCH 8192

// ws layout (float offsets)
#define WS_PC     0        // 50*240 packed consts
#define WS_DIRECT 12288    // 8192
#define WS_O0     20480    // 100*8192
#define WS_TORQ   839680   // 100*8192 torque accumulator

// ---------------------------------------------------------------------------
// Prep: zero torq accumulator + pack per-osc constants in contiguous-run
// layout (40-float run per operand):
//   pc[o*240 +   0.. 39] = e0[n]   (enc[o][n][0])
//   pc[o*240 +  40.. 79] = e1[n]   (enc[o][n][1])
//   pc[o*240 +  80..119] = d0[n]   (dec[o][0][n])
//   pc[o*240 + 120..159] = d1[n]   (dec[o][1][n])
//   pc[o*240 + 160..199] = w [n]   (fc4_w[o*40+n])
//   pc[o*240 + 200..239] = ob[n]   (obias[o][n])
// ---------------------------------------------------------------------------
__global__ __launch_bounds__(256) void prep_kernel(
    const float* __restrict__ enc, const float* __restrict__ obias,
    const float* __restrict__ dec, const float* __restrict__ fc4_w,
    float* __restrict__ pc, float* __restrict__ torq) {
    int idx = blockIdx.x * 256 + threadIdx.x;
    ((float4*)torq)[idx] = make_float4(0.f, 0.f, 0.f, 0.f);   // 800*256*4 = 819200
    if (idx < N_OSC * N_PER) {
        int o = idx / N_PER, n = idx - o * N_PER;
        float* base = pc + o * 240;
        base[n]       = enc[o * 80 + 2 * n + 0];
        base[40 + n]  = enc[o * 80 + 2 * n + 1];
        base[80 + n]  = dec[o * 80 + n];
        base[120 + n] = dec[o * 80 + 40 + n];
        base[160 + n] = fc4_w[o * 40 + n];
        base[200 + n] = obias[o * 40 + n];
    }
}

// ---------------------------------------------------------------------------
// MLP prologue. 1024 blocks x 256 threads, 8 batch rows per block.
// ---------------------------------------------------------------------------
__global__ __launch_bounds__(256) void mlp_kernel(
    const float* __restrict__ x,
    const float* __restrict__ fc1_w, const float* __restrict__ fc1_b,
    const float* __restrict__ fc2_w, const float* __restrict__ fc2_b,
    const float* __restrict__ fc3_w, const float* __restrict__ fc3_b,
    const float* __restrict__ fcd_w, const float* __restrict__ fcd_b,
    float* __restrict__ o0out, float* __restrict__ directout) {
    __shared__ float hs[8 * 132];
    __shared__ float h2s[8 * 132];
    int tid = threadIdx.x;
    int bb = tid & 7;
    int hw = tid >> 3;             // 0..31
    int b0 = blockIdx.x * 8;

    // fc1: h = relu(x @ fc1_w.T + b1), 8x128 outputs
    for (int idx = tid; idx < 8 * 128; idx += 256) {
        int r = idx >> 7, j = idx & 127;
        float x0 = x[(b0 + r) * 2], x1 = x[(b0 + r) * 2 + 1];
        float v = fmaf(x0, fc1_w[j * 2], fmaf(x1, fc1_w[j * 2 + 1], fc1_b[j]));
        hs[r * 132 + j] = fmaxf(v, 0.f);
    }
    __syncthreads();

    // direct = h . fcd_w + fcd_b
    if (tid < 8) {
        float s = fcd_b[0];
        #pragma unroll 8
        for (int k = 0; k < 128; k += 4) {
            float4 h4 = *(const float4*)&hs[tid * 132 + k];
            float4 w4 = *(const float4*)&fcd_w[k];
            s = fmaf(h4.x, w4.x, fmaf(h4.y, w4.y, fmaf(h4.z, w4.z, fmaf(h4.w, w4.w, s))));
        }
        directout[b0 + tid] = s;
    }

    // fc2: h2 = relu(h @ fc2_w.T + b2). Each thread: 4 j for its row.
    {
        int j0 = hw * 4;
        float a0 = fc2_b[j0], a1 = fc2_b[j0 + 1], a2 = fc2_b[j0 + 2], a3 = fc2_b[j0 + 3];
        const float* w0 = fc2_w + j0 * 128;
        const float* w1 = w0 + 128;
        const float* w2 = w0 + 256;
        const float* w3 = w0 + 384;
        #pragma unroll 8
        for (int k = 0; k < 128; k += 4) {
            float4 h4 = *(const float4*)&hs[bb * 132 + k];
            float4 q0 = *(const float4*)&w0[k];
            float4 q1 = *(const float4*)&w1[k];
            float4 q2 = *(const float4*)&w2[k];
            float4 q3 = *(const float4*)&w3[k];
            a0 = fmaf(h4.x, q0.x, fmaf(h4.y, q0.y, fmaf(h4.z, q0.z, fmaf(h4.w, q0.w, a0))));
            a1 = fmaf(h4.x, q1.x, fmaf(h4.y, q1.y, fmaf(h4.z, q1.z, fmaf(h4.w, q1.w, a1))));
            a2 = fmaf(h4.x, q2.x, fmaf(h4.y, q2.y, fmaf(h4.z, q2.z, fmaf(h4.w, q2.w, a2))));
            a3 = fmaf(h4.x, q3.x, fmaf(h4.y, q3.y, fmaf(h4.z, q3.z, fmaf(h4.w, q3.w, a3))));
        }
        h2s[bb * 132 + j0]     = fmaxf(a0, 0.f);
        h2s[bb * 132 + j0 + 1] = fmaxf(a1, 0.f);
        h2s[bb * 132 + j0 + 2] = fmaxf(a2, 0.f);
        h2s[bb * 132 + j0 + 3] = fmaxf(a3, 0.f);
    }
    __syncthreads();

    // fc3: x3 = h2 @ fc3_w.T + b3 (100 outputs) -> o0out[j][b]
    {
        int j0 = hw * 4;
        if (j0 < 100) {
            float a0 = fc3_b[j0], a1 = fc3_b[j0 + 1], a2 = fc3_b[j0 + 2], a3 = fc3_b[j0 + 3];
            const float* w0 = fc3_w + j0 * 128;
            const float* w1 = w0 + 128;
            const float* w2 = w0 + 256;
            const float* w3 = w0 + 384;
            #pragma unroll 8
            for (int k = 0; k < 128; k += 4) {
                float4 h4 = *(const float4*)&h2s[bb * 132 + k];
                float4 q0 = *(const float4*)&w0[k];
                float4 q1 = *(const float4*)&w1[k];
                float4 q2 = *(const float4*)&w2[k];
                float4 q3 = *(const float4*)&w3[k];
                a0 = fmaf(h4.x, q0.x, fmaf(h4.y, q0.y, fmaf(h4.z, q0.z, fmaf(h4.w, q0.w, a0))));
                a1 = fmaf(h4.x, q1.x, fmaf(h4.y, q1.y, fmaf(h4.z, q1.z, fmaf(h4.w, q1.w, a1))));
                a2 = fmaf(h4.x, q2.x, fmaf(h4.y, q2.y, fmaf(h4.z, q2.z, fmaf(h4.w, q2.w, a2))));
                a3 = fmaf(h4.x, q3.x, fmaf(h4.y, q3.y, fmaf(h4.z, q3.z, fmaf(h4.w, q3.w, a3))));
            }
            o0out[(j0)     * BATCH + b0 + bb] = a0;
            o0out[(j0 + 1) * BATCH + b0 + bb] = a1;
            o0out[(j0 + 2) * BATCH + b0 + bb] = a2;
            o0out[(j0 + 3) * BATCH + b0 + bb] = a3;
        }
    }
}

// ---------------------------------------------------------------------------
// Phase A (R3): R0's proven VGPR-pinned-constant core, scalarized, with the
// 5-wave per-block atomic reduction.
// - Constants LDS -> VGPRs ONCE, pinned via opaque asm (R0-proven: compiles
//   with zero scratch). Scalar fp32 (not v2f): CDNA4 packed fp32 has no rate
//   advantage (157.3 TF spec = scalar rate), same 200-VGPR footprint, and
//   ob[n] rides each inner fma's single-SGPR operand slot -> deletes R0's
//   40 per-step v_movs and the horizontal .x+.y adds.
// - NO min-waves in launch_bounds: R2's forced bound (320,7) capped VGPRs at
//   73 -> obv spilled to scratch -> 11 GB fetch / 16 GB write, VALU 4.9%.
//   The allocator must be free to keep the 200 pinned floats resident.
// - Block = 5 waves = 5 consecutive oscillators, one 64-row batch group.
//   Per-step parity-double-buffered LDS reduce, ONE atomicAdd per block-step
//   by a rotating wave. R0's counters showed WRITE_SIZE 160 MB at 600 GB/s
//   = the kernel was atomic-write-paced (device atomics bypass per-XCD L2,
//   full HBM write-through). This cuts atomic traffic to 33 MB -> hidden
//   under compute. Barrier is raw s_waitcnt lgkmcnt(0)+s_barrier so the
//   previous step's atomic stays in flight (no vmcnt drain).
// Grid: 1280 blocks (10 osc-groups x 128 bgroups) x 320 threads.
// ---------------------------------------------------------------------------
__global__ __launch_bounds__(320) void osc_kernel(const float* __restrict__ pc,
                                                  const float* __restrict__ o0init,
                                                  float* __restrict__ torq) {
    __shared__ float cs[5][240];
    __shared__ float red[2][5][64];
    int tid = threadIdx.x;
    int lane = tid & 63;
    int wid = __builtin_amdgcn_readfirstlane(tid) >> 6;   // 0..4, SGPR
    int blk = blockIdx.x;
    int g = blk >> 7;              // 0..9  (osc group)
    int bg = blk & 127;            // batch group
    int osc = g * 5 + wid;         // SGPR
    int b = bg * 64 + lane;

    if (lane < 60)
        ((float4*)cs[wid])[lane] = ((const float4*)(pc + osc * 240))[lane];
    __syncthreads();

    // LDS -> VGPR-resident constants (160 floats), pinned so they stay put.
    float e0v[40], e1v[40], d0v[40], d1v[40], wv[40];
    #pragma unroll
    for (int n = 0; n < 40; ++n) {
        e0v[n] = cs[wid][n];
        e1v[n] = cs[wid][40 + n];
        d0v[n] = cs[wid][80 + n];
        d1v[n] = cs[wid][120 + n];
        wv[n]  = cs[wid][160 + n];
    }
    #pragma unroll
    for (int n = 0; n < 40; ++n) {
        asm volatile("" : "+v"(e0v[n]));
        asm volatile("" : "+v"(e1v[n]));
        asm volatile("" : "+v"(d0v[n]));
        asm volatile("" : "+v"(d1v[n]));
        asm volatile("" : "+v"(wv[n]));
    }

    // obias -> SGPRs (wave-uniform); consumed as the fma's SGPR operand.
    float ob[40];
    #pragma unroll
    for (int n = 0; n < 40; ++n) {
        union { float f; int i; } u;
        u.f = cs[wid][200 + n];
        u.i = __builtin_amdgcn_readfirstlane(u.i);
        ob[n] = u.f;
    }

    float s0 = o0init[(2 * osc) * BATCH + b];
    float s1 = o0init[(2 * osc + 1) * BATCH + b];

    int rw = 0;                    // rotating reducer wave
    for (int step = 0; step < STEPS; ++step) {
        float tq = 0.f, D0 = 0.f, D1 = 0.f;
        #pragma unroll
        for (int n = 0; n < 40; ++n) {
            float a = fmaf(s0, e0v[n], fmaf(s1, e1v[n], ob[n]));
            a = fmaxf(a, 0.f);
            tq = fmaf(a, wv[n], tq);
            D0 = fmaf(a, d0v[n], D0);
            D1 = fmaf(a, d1v[n], D1);
        }
        s0 = fmaf(DT, D0, s0);
        s1 = fmaf(DT, D1, s1);

        int par = step & 1;
        red[par][wid][lane] = tq;
        // LDS-visibility barrier WITHOUT vmcnt drain (atomic stays in flight).
        asm volatile("s_waitcnt lgkmcnt(0)\n\ts_barrier" ::: "memory");
        if (wid == rw) {           // scalar branch (wid, rw both SGPR)
            float t = red[par][0][lane] + red[par][1][lane] + red[par][2][lane]
                    + red[par][3][lane] + red[par][4][lane];
            atomicAdd(&torq[step * BATCH + b], t);
        }
        rw = (rw == 4) ? 0 : rw + 1;
    }
}

// ---------------------------------------------------------------------------
// Phase B: integrate pendulum; prefetch torq; packed float2 state store.
// ---------------------------------------------------------------------------
__global__ __launch_bounds__(256) void pend_kernel(const float* __restrict__ x,
                                                   const float* __restrict__ torq,
                                                   const float* __restrict__ direct,
                                                   const float* __restrict__ fc4_b,
                                                   float* __restrict__ out) {
    int b = blockIdx.x * 256 + threadIdx.x;
    float theta = x[2 * b];
    float omega = 0.f;
    float base = direct[b] + fc4_b[0];
    float2* out_l = (float2*)out;             // (100, 8192, 2)
    float* out_t = out + STEPS * BATCH * 2;   // (100, 8192)
    float pf[4];
    #pragma unroll
    for (int j = 0; j < 4; ++j) pf[j] = torq[j * BATCH + b];
    #pragma unroll 4
    for (int s = 0; s < STEPS; ++s) {
        float tq = base + pf[s & 3];
        if (s + 4 < STEPS) pf[s & 3] = torq[(s + 4) * BATCH + b];
        float alpha = tq - __sinf(theta) - 0.1f * omega;   // old theta, old omega
        theta = fmaf(DT, omega, theta);                    // uses old omega
        omega = fmaf(DT, alpha, omega);
        out_l[s * BATCH + b] = make_float2(theta, omega);
        out_t[s * BATCH + b] = tq;
    }
}

extern "C" void kernel_launch(void* const* d_in, const int* in_sizes, int n_in,
                              void* d_out, int out_size, void* d_ws, size_t ws_size,
                              hipStream_t stream) {
    const float* x     = (const float*)d_in[0];
    const float* fc1_w = (const float*)d_in[1];
    const float* fc1_b = (const float*)d_in[2];
    const float* fc2_w = (const float*)d_in[3];
    const float* fc2_b = (const float*)d_in[4];
    const float* fc3_w = (const float*)d_in[5];
    const float* fc3_b = (const float*)d_in[6];
    const float* fcd_w = (const float*)d_in[7];
    const float* fcd_b = (const float*)d_in[8];
    const float* enc   = (const float*)d_in[9];
    const float* obias = (const float*)d_in[10];
    const float* dec   = (const float*)d_in[11];
    const float* fc4_w = (const float*)d_in[12];
    const float* fc4_b = (const float*)d_in[13];
    float* out = (float*)d_out;
    float* ws = (float*)d_ws;

    float* pc      = ws + WS_PC;
    float* direct  = ws + WS_DIRECT;
    float* o0      = ws + WS_O0;
    float* torq    = ws + WS_TORQ;

    hipLaunchKernelGGL(prep_kernel, dim3(STEPS * BATCH / 4 / 256), dim3(256), 0, stream,
                       enc, obias, dec, fc4_w, pc, torq);
    hipLaunchKernelGGL(mlp_kernel, dim3(BATCH / 8), dim3(256), 0, stream,
                       x, fc1_w, fc1_b, fc2_w, fc2_b, fc3_w, fc3_b,
                       fcd_w, fcd_b, o0, direct);
    hipLaunchKernelGGL(osc_kernel, dim3(10 * 128), dim3(320), 0, stream,
                       pc, o0, torq);
    hipLaunchKernelGGL(pend_kernel, dim3(BATCH / 256), dim3(256), 0, stream,
                       x, torq, direct, fc4_b, out);
}

// Round 4
// 627.612 us; speedup vs baseline: 9.3334x; 1.9454x over previous
//
#include <hip/hip_runtime.h>

#define N_OSC 50
#define N_PER 40
#define DT 0.01f
#define STEPS 100
#define BATCH 8192

// ws layout (float offsets)
#define WS_PC     0        // 50*240 packed consts
#define WS_DIRECT 12288    // 8192
#define WS_O0     20480    // 100*8192
#define WS_TORQ   839680   // 100*8192 torque accumulator

// ---------------------------------------------------------------------------
// Prep: zero torq accumulator + pack per-osc constants in contiguous-run
// layout (40-float run per operand):
//   pc[o*240 +   0.. 39] = e0[n]   (enc[o][n][0])
//   pc[o*240 +  40.. 79] = e1[n]   (enc[o][n][1])
//   pc[o*240 +  80..119] = d0[n]   (dec[o][0][n])
//   pc[o*240 + 120..159] = d1[n]   (dec[o][1][n])
//   pc[o*240 + 160..199] = w [n]   (fc4_w[o*40+n])
//   pc[o*240 + 200..239] = ob[n]   (obias[o][n])
// ---------------------------------------------------------------------------
__global__ __launch_bounds__(256) void prep_kernel(
    const float* __restrict__ enc, const float* __restrict__ obias,
    const float* __restrict__ dec, const float* __restrict__ fc4_w,
    float* __restrict__ pc, float* __restrict__ torq) {
    int idx = blockIdx.x * 256 + threadIdx.x;
    ((float4*)torq)[idx] = make_float4(0.f, 0.f, 0.f, 0.f);   // 800*256*4 = 819200
    if (idx < N_OSC * N_PER) {
        int o = idx / N_PER, n = idx - o * N_PER;
        float* base = pc + o * 240;
        base[n]       = enc[o * 80 + 2 * n + 0];
        base[40 + n]  = enc[o * 80 + 2 * n + 1];
        base[80 + n]  = dec[o * 80 + n];
        base[120 + n] = dec[o * 80 + 40 + n];
        base[160 + n] = fc4_w[o * 40 + n];
        base[200 + n] = obias[o * 40 + n];
    }
}

// ---------------------------------------------------------------------------
// MLP prologue. 1024 blocks x 256 threads, 8 batch rows per block.
// ---------------------------------------------------------------------------
__global__ __launch_bounds__(256) void mlp_kernel(
    const float* __restrict__ x,
    const float* __restrict__ fc1_w, const float* __restrict__ fc1_b,
    const float* __restrict__ fc2_w, const float* __restrict__ fc2_b,
    const float* __restrict__ fc3_w, const float* __restrict__ fc3_b,
    const float* __restrict__ fcd_w, const float* __restrict__ fcd_b,
    float* __restrict__ o0out, float* __restrict__ directout) {
    __shared__ float hs[8 * 132];
    __shared__ float h2s[8 * 132];
    int tid = threadIdx.x;
    int bb = tid & 7;
    int hw = tid >> 3;             // 0..31
    int b0 = blockIdx.x * 8;

    // fc1: h = relu(x @ fc1_w.T + b1), 8x128 outputs
    for (int idx = tid; idx < 8 * 128; idx += 256) {
        int r = idx >> 7, j = idx & 127;
        float x0 = x[(b0 + r) * 2], x1 = x[(b0 + r) * 2 + 1];
        float v = fmaf(x0, fc1_w[j * 2], fmaf(x1, fc1_w[j * 2 + 1], fc1_b[j]));
        hs[r * 132 + j] = fmaxf(v, 0.f);
    }
    __syncthreads();

    // direct = h . fcd_w + fcd_b
    if (tid < 8) {
        float s = fcd_b[0];
        #pragma unroll 8
        for (int k = 0; k < 128; k += 4) {
            float4 h4 = *(const float4*)&hs[tid * 132 + k];
            float4 w4 = *(const float4*)&fcd_w[k];
            s = fmaf(h4.x, w4.x, fmaf(h4.y, w4.y, fmaf(h4.z, w4.z, fmaf(h4.w, w4.w, s))));
        }
        directout[b0 + tid] = s;
    }

    // fc2: h2 = relu(h @ fc2_w.T + b2). Each thread: 4 j for its row.
    {
        int j0 = hw * 4;
        float a0 = fc2_b[j0], a1 = fc2_b[j0 + 1], a2 = fc2_b[j0 + 2], a3 = fc2_b[j0 + 3];
        const float* w0 = fc2_w + j0 * 128;
        const float* w1 = w0 + 128;
        const float* w2 = w0 + 256;
        const float* w3 = w0 + 384;
        #pragma unroll 8
        for (int k = 0; k < 128; k += 4) {
            float4 h4 = *(const float4*)&hs[bb * 132 + k];
            float4 q0 = *(const float4*)&w0[k];
            float4 q1 = *(const float4*)&w1[k];
            float4 q2 = *(const float4*)&w2[k];
            float4 q3 = *(const float4*)&w3[k];
            a0 = fmaf(h4.x, q0.x, fmaf(h4.y, q0.y, fmaf(h4.z, q0.z, fmaf(h4.w, q0.w, a0))));
            a1 = fmaf(h4.x, q1.x, fmaf(h4.y, q1.y, fmaf(h4.z, q1.z, fmaf(h4.w, q1.w, a1))));
            a2 = fmaf(h4.x, q2.x, fmaf(h4.y, q2.y, fmaf(h4.z, q2.z, fmaf(h4.w, q2.w, a2))));
            a3 = fmaf(h4.x, q3.x, fmaf(h4.y, q3.y, fmaf(h4.z, q3.z, fmaf(h4.w, q3.w, a3))));
        }
        h2s[bb * 132 + j0]     = fmaxf(a0, 0.f);
        h2s[bb * 132 + j0 + 1] = fmaxf(a1, 0.f);
        h2s[bb * 132 + j0 + 2] = fmaxf(a2, 0.f);
        h2s[bb * 132 + j0 + 3] = fmaxf(a3, 0.f);
    }
    __syncthreads();

    // fc3: x3 = h2 @ fc3_w.T + b3 (100 outputs) -> o0out[j][b]
    {
        int j0 = hw * 4;
        if (j0 < 100) {
            float a0 = fc3_b[j0], a1 = fc3_b[j0 + 1], a2 = fc3_b[j0 + 2], a3 = fc3_b[j0 + 3];
            const float* w0 = fc3_w + j0 * 128;
            const float* w1 = w0 + 128;
            const float* w2 = w0 + 256;
            const float* w3 = w0 + 384;
            #pragma unroll 8
            for (int k = 0; k < 128; k += 4) {
                float4 h4 = *(const float4*)&h2s[bb * 132 + k];
                float4 q0 = *(const float4*)&w0[k];
                float4 q1 = *(const float4*)&w1[k];
                float4 q2 = *(const float4*)&w2[k];
                float4 q3 = *(const float4*)&w3[k];
                a0 = fmaf(h4.x, q0.x, fmaf(h4.y, q0.y, fmaf(h4.z, q0.z, fmaf(h4.w, q0.w, a0))));
                a1 = fmaf(h4.x, q1.x, fmaf(h4.y, q1.y, fmaf(h4.z, q1.z, fmaf(h4.w, q1.w, a1))));
                a2 = fmaf(h4.x, q2.x, fmaf(h4.y, q2.y, fmaf(h4.z, q2.z, fmaf(h4.w, q2.w, a2))));
                a3 = fmaf(h4.x, q3.x, fmaf(h4.y, q3.y, fmaf(h4.z, q3.z, fmaf(h4.w, q3.w, a3))));
            }
            o0out[(j0)     * BATCH + b0 + bb] = a0;
            o0out[(j0 + 1) * BATCH + b0 + bb] = a1;
            o0out[(j0 + 2) * BATCH + b0 + bb] = a2;
            o0out[(j0 + 3) * BATCH + b0 + bb] = a3;
        }
    }
}

// ---------------------------------------------------------------------------
// Phase A (R4): 2 oscillators per wave, NO cross-wave sync.
// R3 post-mortem: the 5-wave per-step s_barrier created convoy stalls
// (VALUBusy 20%, 80% stall, 4.2x regression) -- per-step barriers are banned.
// Instead each wave serially computes 2 oscillators and issues ONE fused
// atomicAdd -> atomic traffic 160 MB (R0) -> 80 MB with zero sync.
// Register plan (gfx950 unified VGPR/AGPR file, both VALU-readable):
//   osc A consts e0,e1,d0,d1,w -> "+v" pinned (200 VGPRs)
//   osc B consts e0,e1,d0,d1,w -> "+a" pinned (200 AGPRs; CDNA2+ VALU can
//     source AGPRs directly, worst case 1 v_accvgpr_read each)
//   obA -> AGPR, obB -> SGPR (keeps every fma at <=1 scalar-file operand)
// ~460 regs/wave -> 4 waves/SIMD -> all 3200 waves resident in one round.
// NO min-waves bound (R2 lesson: forcing occupancy below the pinned-constant
// footprint causes scratch spill catastrophe -- watch FETCH_SIZE to verify).
// Grid: 25 osc-pairs x 128 bgroups, 64-thread blocks (1 wave).
// ---------------------------------------------------------------------------
__global__ __launch_bounds__(64) void osc_kernel(const float* __restrict__ pc,
                                                 const float* __restrict__ o0init,
                                                 float* __restrict__ torq) {
    __shared__ float cs[2][240];
    int lane = threadIdx.x;        // 0..63, one wave per block
    int blk = blockIdx.x;
    int pair = blk >> 7;           // 0..24
    int bg = blk & 127;            // batch group
    int oscA = pair * 2;
    int oscB = oscA + 1;
    int b = bg * 64 + lane;

    if (lane < 60) {
        ((float4*)cs[0])[lane] = ((const float4*)(pc + oscA * 240))[lane];
        ((float4*)cs[1])[lane] = ((const float4*)(pc + oscB * 240))[lane];
    }
    __syncthreads();

    // A-set -> VGPRs, B-set + obA -> AGPRs, pinned so they stay resident.
    float eA0[40], eA1[40], dA0[40], dA1[40], wA[40], obA[40];
    float eB0[40], eB1[40], dB0[40], dB1[40], wB[40];
    #pragma unroll
    for (int n = 0; n < 40; ++n) {
        eA0[n] = cs[0][n];        eA1[n] = cs[0][40 + n];
        dA0[n] = cs[0][80 + n];   dA1[n] = cs[0][120 + n];
        wA[n]  = cs[0][160 + n];  obA[n] = cs[0][200 + n];
        eB0[n] = cs[1][n];        eB1[n] = cs[1][40 + n];
        dB0[n] = cs[1][80 + n];   dB1[n] = cs[1][120 + n];
        wB[n]  = cs[1][160 + n];
    }
    #pragma unroll
    for (int n = 0; n < 40; ++n) {
        asm volatile("" : "+v"(eA0[n]));
        asm volatile("" : "+v"(eA1[n]));
        asm volatile("" : "+v"(dA0[n]));
        asm volatile("" : "+v"(dA1[n]));
        asm volatile("" : "+v"(wA[n]));
        asm volatile("" : "+a"(obA[n]));
        asm volatile("" : "+a"(eB0[n]));
        asm volatile("" : "+a"(eB1[n]));
        asm volatile("" : "+a"(dB0[n]));
        asm volatile("" : "+a"(dB1[n]));
        asm volatile("" : "+a"(wB[n]));
    }

    // obB -> SGPRs (wave-uniform), rides the fma's single scalar operand.
    float obB[40];
    #pragma unroll
    for (int n = 0; n < 40; ++n) {
        union { float f; int i; } u;
        u.f = cs[1][200 + n];
        u.i = __builtin_amdgcn_readfirstlane(u.i);
        obB[n] = u.f;
    }

    float sA0 = o0init[(2 * oscA)     * BATCH + b];
    float sA1 = o0init[(2 * oscA + 1) * BATCH + b];
    float sB0 = o0init[(2 * oscB)     * BATCH + b];
    float sB1 = o0init[(2 * oscB + 1) * BATCH + b];

    for (int step = 0; step < STEPS; ++step) {
        float tq = 0.f;
        float D0 = 0.f, D1 = 0.f;
        #pragma unroll
        for (int n = 0; n < 40; ++n) {
            float a = fmaf(sA0, eA0[n], fmaf(sA1, eA1[n], obA[n]));
            a = fmaxf(a, 0.f);
            tq = fmaf(a, wA[n], tq);
            D0 = fmaf(a, dA0[n], D0);
            D1 = fmaf(a, dA1[n], D1);
        }
        sA0 = fmaf(DT, D0, sA0);
        sA1 = fmaf(DT, D1, sA1);

        D0 = 0.f; D1 = 0.f;
        #pragma unroll
        for (int n = 0; n < 40; ++n) {
            float a = fmaf(sB0, eB0[n], fmaf(sB1, eB1[n], obB[n]));
            a = fmaxf(a, 0.f);
            tq = fmaf(a, wB[n], tq);
            D0 = fmaf(a, dB0[n], D0);
            D1 = fmaf(a, dB1[n], D1);
        }
        sB0 = fmaf(DT, D0, sB0);
        sB1 = fmaf(DT, D1, sB1);

        // One fused atomic per wave-step (fire-and-forget, no readback).
        atomicAdd(&torq[step * BATCH + b], tq);
    }
}

// ---------------------------------------------------------------------------
// Phase B: integrate pendulum; prefetch torq; packed float2 state store.
// ---------------------------------------------------------------------------
__global__ __launch_bounds__(256) void pend_kernel(const float* __restrict__ x,
                                                   const float* __restrict__ torq,
                                                   const float* __restrict__ direct,
                                                   const float* __restrict__ fc4_b,
                                                   float* __restrict__ out) {
    int b = blockIdx.x * 256 + threadIdx.x;
    float theta = x[2 * b];
    float omega = 0.f;
    float base = direct[b] + fc4_b[0];
    float2* out_l = (float2*)out;             // (100, 8192, 2)
    float* out_t = out + STEPS * BATCH * 2;   // (100, 8192)
    float pf[4];
    #pragma unroll
    for (int j = 0; j < 4; ++j) pf[j] = torq[j * BATCH + b];
    #pragma unroll 4
    for (int s = 0; s < STEPS; ++s) {
        float tq = base + pf[s & 3];
        if (s + 4 < STEPS) pf[s & 3] = torq[(s + 4) * BATCH + b];
        float alpha = tq - __sinf(theta) - 0.1f * omega;   // old theta, old omega
        theta = fmaf(DT, omega, theta);                    // uses old omega
        omega = fmaf(DT, alpha, omega);
        out_l[s * BATCH + b] = make_float2(theta, omega);
        out_t[s * BATCH + b] = tq;
    }
}

extern "C" void kernel_launch(void* const* d_in, const int* in_sizes, int n_in,
                              void* d_out, int out_size, void* d_ws, size_t ws_size,
                              hipStream_t stream) {
    const float* x     = (const float*)d_in[0];
    const float* fc1_w = (const float*)d_in[1];
    const float* fc1_b = (const float*)d_in[2];
    const float* fc2_w = (const float*)d_in[3];
    const float* fc2_b = (const float*)d_in[4];
    const float* fc3_w = (const float*)d_in[5];
    const float* fc3_b = (const float*)d_in[6];
    const float* fcd_w = (const float*)d_in[7];
    const float* fcd_b = (const float*)d_in[8];
    const float* enc   = (const float*)d_in[9];
    const float* obias = (const float*)d_in[10];
    const float* dec   = (const float*)d_in[11];
    const float* fc4_w = (const float*)d_in[12];
    const float* fc4_b = (const float*)d_in[13];
    float* out = (float*)d_out;
    float* ws = (float*)d_ws;

    float* pc      = ws + WS_PC;
    float* direct  = ws + WS_DIRECT;
    float* o0      = ws + WS_O0;
    float* torq    = ws + WS_TORQ;

    hipLaunchKernelGGL(prep_kernel, dim3(STEPS * BATCH / 4 / 256), dim3(256), 0, stream,
                       enc, obias, dec, fc4_w, pc, torq);
    hipLaunchKernelGGL(mlp_kernel, dim3(BATCH / 8), dim3(256), 0, stream,
                       x, fc1_w, fc1_b, fc2_w, fc2_b, fc3_w, fc3_b,
                       fcd_w, fcd_b, o0, direct);
    hipLaunchKernelGGL(osc_kernel, dim3(25 * 128), dim3(64), 0, stream,
                       pc, o0, torq);
    hipLaunchKernelGGL(pend_kernel, dim3(BATCH / 256), dim3(256), 0, stream,
                       x, torq, direct, fc4_b, out);
}

// Round 5
// 428.524 us; speedup vs baseline: 13.6697x; 1.4646x over previous
//
#include <hip/hip_runtime.h>

#define N_OSC 50
#define N_PER 40
#define DT 0.01f
#define STEPS 100
#define BATCH 8192

// ws layout (float offsets)
#define WS_PC     0        // 50*240 packed consts
#define WS_DIRECT 12288    // 8192
#define WS_O0     20480    // 100*8192
#define WS_TORQ   839680   // 100*8192 reduced torque
#define WS_PART   1658880  // 50*100*8192 per-osc torque slices (163.84 MB)

// ---------------------------------------------------------------------------
// Prep: pack per-osc constants in contiguous-run layout (40-float runs):
//   pc[o*240 +   0.. 39] = e0[n]; [40..79] = e1[n]; [80..119] = d0[n]
//   [120..159] = d1[n];  [160..199] = w[n]; [200..239] = ob[n]
// ---------------------------------------------------------------------------
__global__ __launch_bounds__(256) void prep_kernel(
    const float* __restrict__ enc, const float* __restrict__ obias,
    const float* __restrict__ dec, const float* __restrict__ fc4_w,
    float* __restrict__ pc) {
    int idx = blockIdx.x * 256 + threadIdx.x;
    if (idx < N_OSC * N_PER) {
        int o = idx / N_PER, n = idx - o * N_PER;
        float* base = pc + o * 240;
        base[n]       = enc[o * 80 + 2 * n + 0];
        base[40 + n]  = enc[o * 80 + 2 * n + 1];
        base[80 + n]  = dec[o * 80 + n];
        base[120 + n] = dec[o * 80 + 40 + n];
        base[160 + n] = fc4_w[o * 40 + n];
        base[200 + n] = obias[o * 40 + n];
    }
}

// Zero torq (atomic-fallback mode only).
__global__ __launch_bounds__(256) void zero_kernel(float* __restrict__ torq) {
    int idx = blockIdx.x * 256 + threadIdx.x;
    ((float4*)torq)[idx] = make_float4(0.f, 0.f, 0.f, 0.f);
}

// ---------------------------------------------------------------------------
// MLP prologue. 1024 blocks x 256 threads, 8 batch rows per block.
// ---------------------------------------------------------------------------
__global__ __launch_bounds__(256) void mlp_kernel(
    const float* __restrict__ x,
    const float* __restrict__ fc1_w, const float* __restrict__ fc1_b,
    const float* __restrict__ fc2_w, const float* __restrict__ fc2_b,
    const float* __restrict__ fc3_w, const float* __restrict__ fc3_b,
    const float* __restrict__ fcd_w, const float* __restrict__ fcd_b,
    float* __restrict__ o0out, float* __restrict__ directout) {
    __shared__ float hs[8 * 132];
    __shared__ float h2s[8 * 132];
    int tid = threadIdx.x;
    int bb = tid & 7;
    int hw = tid >> 3;             // 0..31
    int b0 = blockIdx.x * 8;

    // fc1: h = relu(x @ fc1_w.T + b1), 8x128 outputs
    for (int idx = tid; idx < 8 * 128; idx += 256) {
        int r = idx >> 7, j = idx & 127;
        float x0 = x[(b0 + r) * 2], x1 = x[(b0 + r) * 2 + 1];
        float v = fmaf(x0, fc1_w[j * 2], fmaf(x1, fc1_w[j * 2 + 1], fc1_b[j]));
        hs[r * 132 + j] = fmaxf(v, 0.f);
    }
    __syncthreads();

    // direct = h . fcd_w + fcd_b
    if (tid < 8) {
        float s = fcd_b[0];
        #pragma unroll 8
        for (int k = 0; k < 128; k += 4) {
            float4 h4 = *(const float4*)&hs[tid * 132 + k];
            float4 w4 = *(const float4*)&fcd_w[k];
            s = fmaf(h4.x, w4.x, fmaf(h4.y, w4.y, fmaf(h4.z, w4.z, fmaf(h4.w, w4.w, s))));
        }
        directout[b0 + tid] = s;
    }

    // fc2: h2 = relu(h @ fc2_w.T + b2). Each thread: 4 j for its row.
    {
        int j0 = hw * 4;
        float a0 = fc2_b[j0], a1 = fc2_b[j0 + 1], a2 = fc2_b[j0 + 2], a3 = fc2_b[j0 + 3];
        const float* w0 = fc2_w + j0 * 128;
        const float* w1 = w0 + 128;
        const float* w2 = w0 + 256;
        const float* w3 = w0 + 384;
        #pragma unroll 8
        for (int k = 0; k < 128; k += 4) {
            float4 h4 = *(const float4*)&hs[bb * 132 + k];
            float4 q0 = *(const float4*)&w0[k];
            float4 q1 = *(const float4*)&w1[k];
            float4 q2 = *(const float4*)&w2[k];
            float4 q3 = *(const float4*)&w3[k];
            a0 = fmaf(h4.x, q0.x, fmaf(h4.y, q0.y, fmaf(h4.z, q0.z, fmaf(h4.w, q0.w, a0))));
            a1 = fmaf(h4.x, q1.x, fmaf(h4.y, q1.y, fmaf(h4.z, q1.z, fmaf(h4.w, q1.w, a1))));
            a2 = fmaf(h4.x, q2.x, fmaf(h4.y, q2.y, fmaf(h4.z, q2.z, fmaf(h4.w, q2.w, a2))));
            a3 = fmaf(h4.x, q3.x, fmaf(h4.y, q3.y, fmaf(h4.z, q3.z, fmaf(h4.w, q3.w, a3))));
        }
        h2s[bb * 132 + j0]     = fmaxf(a0, 0.f);
        h2s[bb * 132 + j0 + 1] = fmaxf(a1, 0.f);
        h2s[bb * 132 + j0 + 2] = fmaxf(a2, 0.f);
        h2s[bb * 132 + j0 + 3] = fmaxf(a3, 0.f);
    }
    __syncthreads();

    // fc3: x3 = h2 @ fc3_w.T + b3 (100 outputs) -> o0out[j][b]
    {
        int j0 = hw * 4;
        if (j0 < 100) {
            float a0 = fc3_b[j0], a1 = fc3_b[j0 + 1], a2 = fc3_b[j0 + 2], a3 = fc3_b[j0 + 3];
            const float* w0 = fc3_w + j0 * 128;
            const float* w1 = w0 + 128;
            const float* w2 = w0 + 256;
            const float* w3 = w0 + 384;
            #pragma unroll 8
            for (int k = 0; k < 128; k += 4) {
                float4 h4 = *(const float4*)&h2s[bb * 132 + k];
                float4 q0 = *(const float4*)&w0[k];
                float4 q1 = *(const float4*)&w1[k];
                float4 q2 = *(const float4*)&w2[k];
                float4 q3 = *(const float4*)&w3[k];
                a0 = fmaf(h4.x, q0.x, fmaf(h4.y, q0.y, fmaf(h4.z, q0.z, fmaf(h4.w, q0.w, a0))));
                a1 = fmaf(h4.x, q1.x, fmaf(h4.y, q1.y, fmaf(h4.z, q1.z, fmaf(h4.w, q1.w, a1))));
                a2 = fmaf(h4.x, q2.x, fmaf(h4.y, q2.y, fmaf(h4.z, q2.z, fmaf(h4.w, q2.w, a2))));
                a3 = fmaf(h4.x, q3.x, fmaf(h4.y, q3.y, fmaf(h4.z, q3.z, fmaf(h4.w, q3.w, a3))));
            }
            o0out[(j0)     * BATCH + b0 + bb] = a0;
            o0out[(j0 + 1) * BATCH + b0 + bb] = a1;
            o0out[(j0 + 2) * BATCH + b0 + bb] = a2;
            o0out[(j0 + 3) * BATCH + b0 + bb] = a3;
        }
    }
}

// ---------------------------------------------------------------------------
// Phase A (R5): 1 osc/wave scalar core (proven R3 compute), ZERO sync, and
// NO atomics in store mode.
// Lessons baked in: R2 = never force occupancy below the pinned footprint;
// R3 = never barrier per step; R4 = never exceed ~256 regs/wave (AGPR pins
// caused 1 wave/SIMD + cross-file move bloat).
// Register plan: 200 consts "+v"-pinned + ob in SGPRs (readfirstlane) +
// ~25 overhead ≈ 230 VGPR, NO AGPRs -> 2 waves/SIMD.
// MODE 0 (store): each wave writes its torque to a PRIVATE slice
//   partial[osc][step][b] with a plain coalesced store (fire-and-forget,
//   full-BW write-back, no RMW serialization at the coherence point).
//   R0's counters showed the 160 MB atomic RMW write-through paced the
//   kernel at ~600 GB/s; plain stores stream at ~6 TB/s.
// MODE 1 (atomic fallback, if ws too small): per-wave atomicAdd as in R0.
// Grid: 6400 blocks (50 osc x 128 bgroups) x 64 threads.
// ---------------------------------------------------------------------------
template<int MODE>
__global__ __launch_bounds__(64) void osc_kernel(const float* __restrict__ pc,
                                                 const float* __restrict__ o0init,
                                                 float* __restrict__ outbuf) {
    __shared__ float cs[240];
    int lane = threadIdx.x;        // 0..63, one wave per block
    int blk = blockIdx.x;
    int osc = blk >> 7;            // 0..49
    int bg = blk & 127;            // batch group
    int b = bg * 64 + lane;

    if (lane < 60)
        ((float4*)cs)[lane] = ((const float4*)(pc + osc * 240))[lane];
    __syncthreads();

    // LDS -> VGPR-resident constants (200 floats), pinned so they stay put.
    float e0v[40], e1v[40], d0v[40], d1v[40], wv[40];
    #pragma unroll
    for (int n = 0; n < 40; ++n) {
        e0v[n] = cs[n];
        e1v[n] = cs[40 + n];
        d0v[n] = cs[80 + n];
        d1v[n] = cs[120 + n];
        wv[n]  = cs[160 + n];
    }
    #pragma unroll
    for (int n = 0; n < 40; ++n) {
        asm volatile("" : "+v"(e0v[n]));
        asm volatile("" : "+v"(e1v[n]));
        asm volatile("" : "+v"(d0v[n]));
        asm volatile("" : "+v"(d1v[n]));
        asm volatile("" : "+v"(wv[n]));
    }

    // obias -> SGPRs (wave-uniform); rides each fma's single scalar operand.
    float ob[40];
    #pragma unroll
    for (int n = 0; n < 40; ++n) {
        union { float f; int i; } u;
        u.f = cs[200 + n];
        u.i = __builtin_amdgcn_readfirstlane(u.i);
        ob[n] = u.f;
    }

    float s0 = o0init[(2 * osc) * BATCH + b];
    float s1 = o0init[(2 * osc + 1) * BATCH + b];

    // MODE 0: private slice base; MODE 1: shared torq base.
    float* outp = (MODE == 0) ? (outbuf + (size_t)osc * STEPS * BATCH + b)
                              : (outbuf + b);

    for (int step = 0; step < STEPS; ++step) {
        float tq = 0.f, D0 = 0.f, D1 = 0.f;
        #pragma unroll
        for (int n = 0; n < 40; ++n) {
            float a = fmaf(s0, e0v[n], fmaf(s1, e1v[n], ob[n]));
            a = fmaxf(a, 0.f);
            tq = fmaf(a, wv[n], tq);
            D0 = fmaf(a, d0v[n], D0);
            D1 = fmaf(a, d1v[n], D1);
        }
        s0 = fmaf(DT, D0, s0);
        s1 = fmaf(DT, D1, s1);

        if (MODE == 0)
            outp[(size_t)step * BATCH] = tq;         // plain coalesced store
        else
            atomicAdd(&outp[(size_t)step * BATCH], tq);
    }
}

// ---------------------------------------------------------------------------
// Reduce: torq[step][b] = sum over 50 per-osc partials. Pure streaming:
// 164 MB read + 3.3 MB write, float4-vectorized, 800 blocks x 256 threads
// (3200 waves). BW-bound, ~30 us at achievable HBM rate.
// ---------------------------------------------------------------------------
__global__ __launch_bounds__(256) void reduce_kernel(const float* __restrict__ part,
                                                     float* __restrict__ torq) {
    int i = blockIdx.x * 256 + threadIdx.x;          // float4 index, 204800 total
    const float4* p = (const float4*)part;
    float4 s0 = make_float4(0.f, 0.f, 0.f, 0.f);
    float4 s1 = make_float4(0.f, 0.f, 0.f, 0.f);
    #pragma unroll 5
    for (int o = 0; o < N_OSC; o += 2) {             // 2 accumulators for ILP
        float4 v0 = p[(size_t)o * 204800 + i];
        float4 v1 = p[(size_t)(o + 1) * 204800 + i];
        s0.x += v0.x; s0.y += v0.y; s0.z += v0.z; s0.w += v0.w;
        s1.x += v1.x; s1.y += v1.y; s1.z += v1.z; s1.w += v1.w;
    }
    ((float4*)torq)[i] = make_float4(s0.x + s1.x, s0.y + s1.y,
                                     s0.z + s1.z, s0.w + s1.w);
}

// ---------------------------------------------------------------------------
// Phase B: integrate pendulum; prefetch torq; packed float2 state store.
// ---------------------------------------------------------------------------
__global__ __launch_bounds__(256) void pend_kernel(const float* __restrict__ x,
                                                   const float* __restrict__ torq,
                                                   const float* __restrict__ direct,
                                                   const float* __restrict__ fc4_b,
                                                   float* __restrict__ out) {
    int b = blockIdx.x * 256 + threadIdx.x;
    float theta = x[2 * b];
    float omega = 0.f;
    float base = direct[b] + fc4_b[0];
    float2* out_l = (float2*)out;             // (100, 8192, 2)
    float* out_t = out + STEPS * BATCH * 2;   // (100, 8192)
    float pf[4];
    #pragma unroll
    for (int j = 0; j < 4; ++j) pf[j] = torq[j * BATCH + b];
    #pragma unroll 4
    for (int s = 0; s < STEPS; ++s) {
        float tq = base + pf[s & 3];
        if (s + 4 < STEPS) pf[s & 3] = torq[(s + 4) * BATCH + b];
        float alpha = tq - __sinf(theta) - 0.1f * omega;   // old theta, old omega
        theta = fmaf(DT, omega, theta);                    // uses old omega
        omega = fmaf(DT, alpha, omega);
        out_l[s * BATCH + b] = make_float2(theta, omega);
        out_t[s * BATCH + b] = tq;
    }
}

extern "C" void kernel_launch(void* const* d_in, const int* in_sizes, int n_in,
                              void* d_out, int out_size, void* d_ws, size_t ws_size,
                              hipStream_t stream) {
    const float* x     = (const float*)d_in[0];
    const float* fc1_w = (const float*)d_in[1];
    const float* fc1_b = (const float*)d_in[2];
    const float* fc2_w = (const float*)d_in[3];
    const float* fc2_b = (const float*)d_in[4];
    const float* fc3_w = (const float*)d_in[5];
    const float* fc3_b = (const float*)d_in[6];
    const float* fcd_w = (const float*)d_in[7];
    const float* fcd_b = (const float*)d_in[8];
    const float* enc   = (const float*)d_in[9];
    const float* obias = (const float*)d_in[10];
    const float* dec   = (const float*)d_in[11];
    const float* fc4_w = (const float*)d_in[12];
    const float* fc4_b = (const float*)d_in[13];
    float* out = (float*)d_out;
    float* ws = (float*)d_ws;

    float* pc      = ws + WS_PC;
    float* direct  = ws + WS_DIRECT;
    float* o0      = ws + WS_O0;
    float* torq    = ws + WS_TORQ;
    float* part    = ws + WS_PART;

    size_t need_bytes = ((size_t)WS_PART + (size_t)N_OSC * STEPS * BATCH) * sizeof(float);
    bool store_mode = ws_size >= need_bytes;

    hipLaunchKernelGGL(prep_kernel, dim3(8), dim3(256), 0, stream,
                       enc, obias, dec, fc4_w, pc);
    hipLaunchKernelGGL(mlp_kernel, dim3(BATCH / 8), dim3(256), 0, stream,
                       x, fc1_w, fc1_b, fc2_w, fc2_b, fc3_w, fc3_b,
                       fcd_w, fcd_b, o0, direct);
    if (store_mode) {
        hipLaunchKernelGGL(osc_kernel<0>, dim3(N_OSC * 128), dim3(64), 0, stream,
                           pc, o0, part);
        hipLaunchKernelGGL(reduce_kernel, dim3(STEPS * BATCH / 4 / 256), dim3(256),
                           0, stream, part, torq);
    } else {
        hipLaunchKernelGGL(zero_kernel, dim3(STEPS * BATCH / 4 / 256), dim3(256),
                           0, stream, torq);
        hipLaunchKernelGGL(osc_kernel<1>, dim3(N_OSC * 128), dim3(64), 0, stream,
                           pc, o0, torq);
    }
    hipLaunchKernelGGL(pend_kernel, dim3(BATCH / 256), dim3(256), 0, stream,
                       x, torq, direct, fc4_b, out);
}

// Round 6
// 427.449 us; speedup vs baseline: 13.7040x; 1.0025x over previous
//
#include <hip/hip_runtime.h>

#define N_OSC 50
#define N_PER 40
#define DT 0.01f
#define STEPS 100
#define BATCH 8192

// ws layout (float offsets)
#define WS_PC     0        // 50*240 packed consts
#define WS_DIRECT 12288    // 8192
#define WS_O0     20480    // 100*8192
#define WS_TORQ   839680   // 100*8192 reduced torque
#define WS_PART   1658880  // 50*100*8192 per-osc torque slices (163.84 MB)

// ---------------------------------------------------------------------------
// Prep: pack per-osc constants in contiguous-run layout (40-float runs):
//   pc[o*240 +   0.. 39] = e0[n]; [40..79] = e1[n]; [80..119] = d0[n]
//   [120..159] = d1[n];  [160..199] = w[n]; [200..239] = ob[n]
// ---------------------------------------------------------------------------
__global__ __launch_bounds__(256) void prep_kernel(
    const float* __restrict__ enc, const float* __restrict__ obias,
    const float* __restrict__ dec, const float* __restrict__ fc4_w,
    float* __restrict__ pc) {
    int idx = blockIdx.x * 256 + threadIdx.x;
    if (idx < N_OSC * N_PER) {
        int o = idx / N_PER, n = idx - o * N_PER;
        float* base = pc + o * 240;
        base[n]       = enc[o * 80 + 2 * n + 0];
        base[40 + n]  = enc[o * 80 + 2 * n + 1];
        base[80 + n]  = dec[o * 80 + n];
        base[120 + n] = dec[o * 80 + 40 + n];
        base[160 + n] = fc4_w[o * 40 + n];
        base[200 + n] = obias[o * 40 + n];
    }
}

// Zero torq (atomic-fallback mode only).
__global__ __launch_bounds__(256) void zero_kernel(float* __restrict__ torq) {
    int idx = blockIdx.x * 256 + threadIdx.x;
    ((float4*)torq)[idx] = make_float4(0.f, 0.f, 0.f, 0.f);
}

// ---------------------------------------------------------------------------
// MLP prologue. 1024 blocks x 256 threads, 8 batch rows per block.
// ---------------------------------------------------------------------------
__global__ __launch_bounds__(256) void mlp_kernel(
    const float* __restrict__ x,
    const float* __restrict__ fc1_w, const float* __restrict__ fc1_b,
    const float* __restrict__ fc2_w, const float* __restrict__ fc2_b,
    const float* __restrict__ fc3_w, const float* __restrict__ fc3_b,
    const float* __restrict__ fcd_w, const float* __restrict__ fcd_b,
    float* __restrict__ o0out, float* __restrict__ directout) {
    __shared__ float hs[8 * 132];
    __shared__ float h2s[8 * 132];
    int tid = threadIdx.x;
    int bb = tid & 7;
    int hw = tid >> 3;             // 0..31
    int b0 = blockIdx.x * 8;

    // fc1: h = relu(x @ fc1_w.T + b1), 8x128 outputs
    for (int idx = tid; idx < 8 * 128; idx += 256) {
        int r = idx >> 7, j = idx & 127;
        float x0 = x[(b0 + r) * 2], x1 = x[(b0 + r) * 2 + 1];
        float v = fmaf(x0, fc1_w[j * 2], fmaf(x1, fc1_w[j * 2 + 1], fc1_b[j]));
        hs[r * 132 + j] = fmaxf(v, 0.f);
    }
    __syncthreads();

    // direct = h . fcd_w + fcd_b
    if (tid < 8) {
        float s = fcd_b[0];
        #pragma unroll 8
        for (int k = 0; k < 128; k += 4) {
            float4 h4 = *(const float4*)&hs[tid * 132 + k];
            float4 w4 = *(const float4*)&fcd_w[k];
            s = fmaf(h4.x, w4.x, fmaf(h4.y, w4.y, fmaf(h4.z, w4.z, fmaf(h4.w, w4.w, s))));
        }
        directout[b0 + tid] = s;
    }

    // fc2: h2 = relu(h @ fc2_w.T + b2). Each thread: 4 j for its row.
    {
        int j0 = hw * 4;
        float a0 = fc2_b[j0], a1 = fc2_b[j0 + 1], a2 = fc2_b[j0 + 2], a3 = fc2_b[j0 + 3];
        const float* w0 = fc2_w + j0 * 128;
        const float* w1 = w0 + 128;
        const float* w2 = w0 + 256;
        const float* w3 = w0 + 384;
        #pragma unroll 8
        for (int k = 0; k < 128; k += 4) {
            float4 h4 = *(const float4*)&hs[bb * 132 + k];
            float4 q0 = *(const float4*)&w0[k];
            float4 q1 = *(const float4*)&w1[k];
            float4 q2 = *(const float4*)&w2[k];
            float4 q3 = *(const float4*)&w3[k];
            a0 = fmaf(h4.x, q0.x, fmaf(h4.y, q0.y, fmaf(h4.z, q0.z, fmaf(h4.w, q0.w, a0))));
            a1 = fmaf(h4.x, q1.x, fmaf(h4.y, q1.y, fmaf(h4.z, q1.z, fmaf(h4.w, q1.w, a1))));
            a2 = fmaf(h4.x, q2.x, fmaf(h4.y, q2.y, fmaf(h4.z, q2.z, fmaf(h4.w, q2.w, a2))));
            a3 = fmaf(h4.x, q3.x, fmaf(h4.y, q3.y, fmaf(h4.z, q3.z, fmaf(h4.w, q3.w, a3))));
        }
        h2s[bb * 132 + j0]     = fmaxf(a0, 0.f);
        h2s[bb * 132 + j0 + 1] = fmaxf(a1, 0.f);
        h2s[bb * 132 + j0 + 2] = fmaxf(a2, 0.f);
        h2s[bb * 132 + j0 + 3] = fmaxf(a3, 0.f);
    }
    __syncthreads();

    // fc3: x3 = h2 @ fc3_w.T + b3 (100 outputs) -> o0out[j][b]
    {
        int j0 = hw * 4;
        if (j0 < 100) {
            float a0 = fc3_b[j0], a1 = fc3_b[j0 + 1], a2 = fc3_b[j0 + 2], a3 = fc3_b[j0 + 3];
            const float* w0 = fc3_w + j0 * 128;
            const float* w1 = w0 + 128;
            const float* w2 = w0 + 256;
            const float* w3 = w0 + 384;
            #pragma unroll 8
            for (int k = 0; k < 128; k += 4) {
                float4 h4 = *(const float4*)&h2s[bb * 132 + k];
                float4 q0 = *(const float4*)&w0[k];
                float4 q1 = *(const float4*)&w1[k];
                float4 q2 = *(const float4*)&w2[k];
                float4 q3 = *(const float4*)&w3[k];
                a0 = fmaf(h4.x, q0.x, fmaf(h4.y, q0.y, fmaf(h4.z, q0.z, fmaf(h4.w, q0.w, a0))));
                a1 = fmaf(h4.x, q1.x, fmaf(h4.y, q1.y, fmaf(h4.z, q1.z, fmaf(h4.w, q1.w, a1))));
                a2 = fmaf(h4.x, q2.x, fmaf(h4.y, q2.y, fmaf(h4.z, q2.z, fmaf(h4.w, q2.w, a2))));
                a3 = fmaf(h4.x, q3.x, fmaf(h4.y, q3.y, fmaf(h4.z, q3.z, fmaf(h4.w, q3.w, a3))));
            }
            o0out[(j0)     * BATCH + b0 + bb] = a0;
            o0out[(j0 + 1) * BATCH + b0 + bb] = a1;
            o0out[(j0 + 2) * BATCH + b0 + bb] = a2;
            o0out[(j0 + 3) * BATCH + b0 + bb] = a3;
        }
    }
}

// ---------------------------------------------------------------------------
// Phase A (R6): identical structure to R5 (1 osc/wave, zero sync, plain
// private-slice stores), ONE change: __launch_bounds__(64, 2).
// R5 post-mortem: with no min-waves spec the allocator targeted ~4 waves/SIMD
// by parking the 200 pinned constants in AGPRs (VGPR_Count=116) and paying a
// cross-file move per constant use per step. Measured VALU issue 230 us =
// ideal 127 us + 200 moves x 2 cy/step (104 us) -- exact match.
// min-waves=2 -> VGPR cap 256 > footprint (~230): constants stay in arch
// VGPRs, zero AGPR traffic, 2 waves/SIMD (enough TLP: 4 independent dep
// chains per wave). NOT R2's mistake: R2 forced budget BELOW the footprint
// (73 < 240 -> scratch catastrophe); this forces it ABOVE.
// Tripwire: VGPR_Count==256 AND FETCH_SIZE at MB scale => spill => revert.
// Grid: 6400 blocks (50 osc x 128 bgroups) x 64 threads.
// ---------------------------------------------------------------------------
template<int MODE>
__global__ __launch_bounds__(64, 2) void osc_kernel(const float* __restrict__ pc,
                                                    const float* __restrict__ o0init,
                                                    float* __restrict__ outbuf) {
    __shared__ float cs[240];
    int lane = threadIdx.x;        // 0..63, one wave per block
    int blk = blockIdx.x;
    int osc = blk >> 7;            // 0..49
    int bg = blk & 127;            // batch group
    int b = bg * 64 + lane;

    if (lane < 60)
        ((float4*)cs)[lane] = ((const float4*)(pc + osc * 240))[lane];
    __syncthreads();

    // LDS -> VGPR-resident constants (200 floats), pinned so they stay put.
    float e0v[40], e1v[40], d0v[40], d1v[40], wv[40];
    #pragma unroll
    for (int n = 0; n < 40; ++n) {
        e0v[n] = cs[n];
        e1v[n] = cs[40 + n];
        d0v[n] = cs[80 + n];
        d1v[n] = cs[120 + n];
        wv[n]  = cs[160 + n];
    }
    #pragma unroll
    for (int n = 0; n < 40; ++n) {
        asm volatile("" : "+v"(e0v[n]));
        asm volatile("" : "+v"(e1v[n]));
        asm volatile("" : "+v"(d0v[n]));
        asm volatile("" : "+v"(d1v[n]));
        asm volatile("" : "+v"(wv[n]));
    }

    // obias -> SGPRs (wave-uniform); rides each fma's single scalar operand.
    float ob[40];
    #pragma unroll
    for (int n = 0; n < 40; ++n) {
        union { float f; int i; } u;
        u.f = cs[200 + n];
        u.i = __builtin_amdgcn_readfirstlane(u.i);
        ob[n] = u.f;
    }

    float s0 = o0init[(2 * osc) * BATCH + b];
    float s1 = o0init[(2 * osc + 1) * BATCH + b];

    // MODE 0: private slice base; MODE 1: shared torq base.
    float* outp = (MODE == 0) ? (outbuf + (size_t)osc * STEPS * BATCH + b)
                              : (outbuf + b);

    for (int step = 0; step < STEPS; ++step) {
        float tq = 0.f, D0 = 0.f, D1 = 0.f;
        #pragma unroll
        for (int n = 0; n < 40; ++n) {
            float a = fmaf(s0, e0v[n], fmaf(s1, e1v[n], ob[n]));
            a = fmaxf(a, 0.f);
            tq = fmaf(a, wv[n], tq);
            D0 = fmaf(a, d0v[n], D0);
            D1 = fmaf(a, d1v[n], D1);
        }
        s0 = fmaf(DT, D0, s0);
        s1 = fmaf(DT, D1, s1);

        if (MODE == 0)
            outp[(size_t)step * BATCH] = tq;         // plain coalesced store
        else
            atomicAdd(&outp[(size_t)step * BATCH], tq);
    }
}

// ---------------------------------------------------------------------------
// Reduce: torq[step][b] = sum over 50 per-osc partials. Pure streaming:
// 164 MB read + 3.3 MB write, float4-vectorized, 800 blocks x 256 threads.
// ---------------------------------------------------------------------------
__global__ __launch_bounds__(256) void reduce_kernel(const float* __restrict__ part,
                                                     float* __restrict__ torq) {
    int i = blockIdx.x * 256 + threadIdx.x;          // float4 index, 204800 total
    const float4* p = (const float4*)part;
    float4 s0 = make_float4(0.f, 0.f, 0.f, 0.f);
    float4 s1 = make_float4(0.f, 0.f, 0.f, 0.f);
    #pragma unroll 5
    for (int o = 0; o < N_OSC; o += 2) {             // 2 accumulators for ILP
        float4 v0 = p[(size_t)o * 204800 + i];
        float4 v1 = p[(size_t)(o + 1) * 204800 + i];
        s0.x += v0.x; s0.y += v0.y; s0.z += v0.z; s0.w += v0.w;
        s1.x += v1.x; s1.y += v1.y; s1.z += v1.z; s1.w += v1.w;
    }
    ((float4*)torq)[i] = make_float4(s0.x + s1.x, s0.y + s1.y,
                                     s0.z + s1.z, s0.w + s1.w);
}

// ---------------------------------------------------------------------------
// Phase B: integrate pendulum; prefetch torq; packed float2 state store.
// ---------------------------------------------------------------------------
__global__ __launch_bounds__(256) void pend_kernel(const float* __restrict__ x,
                                                   const float* __restrict__ torq,
                                                   const float* __restrict__ direct,
                                                   const float* __restrict__ fc4_b,
                                                   float* __restrict__ out) {
    int b = blockIdx.x * 256 + threadIdx.x;
    float theta = x[2 * b];
    float omega = 0.f;
    float base = direct[b] + fc4_b[0];
    float2* out_l = (float2*)out;             // (100, 8192, 2)
    float* out_t = out + STEPS * BATCH * 2;   // (100, 8192)
    float pf[4];
    #pragma unroll
    for (int j = 0; j < 4; ++j) pf[j] = torq[j * BATCH + b];
    #pragma unroll 4
    for (int s = 0; s < STEPS; ++s) {
        float tq = base + pf[s & 3];
        if (s + 4 < STEPS) pf[s & 3] = torq[(s + 4) * BATCH + b];
        float alpha = tq - __sinf(theta) - 0.1f * omega;   // old theta, old omega
        theta = fmaf(DT, omega, theta);                    // uses old omega
        omega = fmaf(DT, alpha, omega);
        out_l[s * BATCH + b] = make_float2(theta, omega);
        out_t[s * BATCH + b] = tq;
    }
}

extern "C" void kernel_launch(void* const* d_in, const int* in_sizes, int n_in,
                              void* d_out, int out_size, void* d_ws, size_t ws_size,
                              hipStream_t stream) {
    const float* x     = (const float*)d_in[0];
    const float* fc1_w = (const float*)d_in[1];
    const float* fc1_b = (const float*)d_in[2];
    const float* fc2_w = (const float*)d_in[3];
    const float* fc2_b = (const float*)d_in[4];
    const float* fc3_w = (const float*)d_in[5];
    const float* fc3_b = (const float*)d_in[6];
    const float* fcd_w = (const float*)d_in[7];
    const float* fcd_b = (const float*)d_in[8];
    const float* enc   = (const float*)d_in[9];
    const float* obias = (const float*)d_in[10];
    const float* dec   = (const float*)d_in[11];
    const float* fc4_w = (const float*)d_in[12];
    const float* fc4_b = (const float*)d_in[13];
    float* out = (float*)d_out;
    float* ws = (float*)d_ws;

    float* pc      = ws + WS_PC;
    float* direct  = ws + WS_DIRECT;
    float* o0      = ws + WS_O0;
    float* torq    = ws + WS_TORQ;
    float* part    = ws + WS_PART;

    size_t need_bytes = ((size_t)WS_PART + (size_t)N_OSC * STEPS * BATCH) * sizeof(float);
    bool store_mode = ws_size >= need_bytes;

    hipLaunchKernelGGL(prep_kernel, dim3(8), dim3(256), 0, stream,
                       enc, obias, dec, fc4_w, pc);
    hipLaunchKernelGGL(mlp_kernel, dim3(BATCH / 8), dim3(256), 0, stream,
                       x, fc1_w, fc1_b, fc2_w, fc2_b, fc3_w, fc3_b,
                       fcd_w, fcd_b, o0, direct);
    if (store_mode) {
        hipLaunchKernelGGL(osc_kernel<0>, dim3(N_OSC * 128), dim3(64), 0, stream,
                           pc, o0, part);
        hipLaunchKernelGGL(reduce_kernel, dim3(STEPS * BATCH / 4 / 256), dim3(256),
                           0, stream, part, torq);
    } else {
        hipLaunchKernelGGL(zero_kernel, dim3(STEPS * BATCH / 4 / 256), dim3(256),
                           0, stream, torq);
        hipLaunchKernelGGL(osc_kernel<1>, dim3(N_OSC * 128), dim3(64), 0, stream,
                           pc, o0, torq);
    }
    hipLaunchKernelGGL(pend_kernel, dim3(BATCH / 256), dim3(256), 0, stream,
                       x, torq, direct, fc4_b, out);
}